// Round 5
// baseline (287.059 us; speedup 1.0000x reference)
//
#include <hip/hip_runtime.h>
#include <stdint.h>

#define SEQ 2048
#define C3 3072
#define C1 1024

typedef __bf16 bf16x8 __attribute__((ext_vector_type(8)));
typedef short short8 __attribute__((ext_vector_type(8)));
typedef float f32x4 __attribute__((ext_vector_type(4)));
typedef float f32x16 __attribute__((ext_vector_type(16)));
typedef unsigned uintx2 __attribute__((ext_vector_type(2)));
typedef const __attribute__((address_space(1))) void gv_t;
typedef __attribute__((address_space(3))) void lv_t;

#if __has_builtin(__builtin_amdgcn_exp2f)
#define EXP2(x) __builtin_amdgcn_exp2f(x)
#else
#define EXP2(x) exp2f(x)
#endif

static __device__ __forceinline__ unsigned short f2bf(float f) {
  union { float ff; unsigned u; } x; x.ff = f;
  unsigned u = x.u + 0x7FFFu + ((x.u >> 16) & 1u);
  return (unsigned short)(u >> 16);
}
static __device__ __forceinline__ unsigned rne2(float lo, float hi) {
  return (unsigned)f2bf(lo) | ((unsigned)f2bf(hi) << 16);
}
// pack top halves of two f32 -> one bf16x2 dword (truncation; P in [0,1])
static __device__ __forceinline__ unsigned pk2(float lo, float hi) {
  union { float f; unsigned u; } a, b; a.f = lo; b.f = hi;
  return __builtin_amdgcn_perm(b.u, a.u, 0x07060302);
}

// v_permlane32_swap_b32: vdst upper 32 lanes <-> src lower 32 lanes.
// out0[l] = l<32 ? a[l] : b[l-32];  out1[l] = l<32 ? a[l+32] : b[l]
static __device__ __forceinline__ void plswap(unsigned a, unsigned b,
                                              unsigned& o0, unsigned& o1) {
#if __has_builtin(__builtin_amdgcn_permlane32_swap)
  uintx2 r = __builtin_amdgcn_permlane32_swap(a, b, false, false);
  o0 = r[0]; o1 = r[1];
#else
  asm volatile("v_permlane32_swap_b32 %0, %1" : "+v"(a), "+v"(b));
  o0 = a; o1 = b;
#endif
}

// fused fp32->bf16 convert for x | w_qkv | w_out (one launch, 3 ranges)
__global__ void k_cvt3(const float* __restrict__ ia, const float* __restrict__ ib,
                       const float* __restrict__ ic, unsigned short* __restrict__ oa,
                       unsigned short* __restrict__ ob, unsigned short* __restrict__ oc) {
  int blk = blockIdx.x;
  const float* in; unsigned short* out; int base;
  if (blk < 8192)      { in = ia; out = oa; base = blk; }
  else if (blk < 11264){ in = ib; out = ob; base = blk - 8192; }
  else                 { in = ic; out = oc; base = blk - 11264; }
  int i = base * 256 + threadIdx.x;
  f32x4 v = ((const f32x4*)in)[i];
  ushort4 o;
  o.x = f2bf(v[0]); o.y = f2bf(v[1]); o.z = f2bf(v[2]); o.w = f2bf(v[3]);
  ((ushort4*)out)[i] = o;
}

// C[M,N] = A[M,K] @ B[N,K]^T, bf16 in, BK=64.
// MODE 0: bf16 out; cols<1024 scaled by 0.125*log2(e) (Q prescale); V columns
// (n0>=2048, block-uniform) written TRANSPOSED to vTout[(b*16+h)*64+d][tok].
// MODE 1: f32 out + bias.
// (Round-3 tried T1 XCD swizzle: regressed 58.4->62.4, FETCH up — inputs are
// L3-resident so swizzle only hurt; reverted per m160's "costs ~2% when L3-fit".)
template<int MODE>
__global__ __launch_bounds__(256, 3) void k_gemm(
    const unsigned short* __restrict__ A, const unsigned short* __restrict__ B,
    void* __restrict__ Cout, const float* __restrict__ bias,
    unsigned short* __restrict__ vTout, int M, int N, int K)
{
  __shared__ unsigned short As[128 * 64];
  __shared__ unsigned short Bs[128 * 64];
  const int tid = threadIdx.x;
  const int w = tid >> 6, l = tid & 63;
  const int lane15 = l & 15, quad = l >> 4;
  const int m0 = blockIdx.y * 128, n0 = blockIdx.x * 128;
  const int wm = (w >> 1) * 64, wn = (w & 1) * 64;

  f32x4 acc[4][4];
#pragma unroll
  for (int i = 0; i < 4; i++)
#pragma unroll
    for (int j = 0; j < 4; j++) acc[i][j] = (f32x4){0.f, 0.f, 0.f, 0.f};

  const int srow = l >> 3;
  const int g_off = ((l & 7) ^ (srow & 7)) * 8;
  const unsigned short* Ab = A + (size_t)(m0 + w * 32 + srow) * K + g_off;
  const unsigned short* Bb = B + (size_t)(n0 + w * 32 + srow) * K + g_off;
  const int rsl = lane15 & 7;

  for (int k0 = 0; k0 < K; k0 += 64) {
    __syncthreads();
#pragma unroll
    for (int i = 0; i < 4; i++) {
      int rb = w * 32 + i * 8;
      __builtin_amdgcn_global_load_lds((gv_t*)(Ab + (size_t)(i * 8) * K + k0),
                                       (lv_t*)&As[rb * 64], 16, 0, 0);
      __builtin_amdgcn_global_load_lds((gv_t*)(Bb + (size_t)(i * 8) * K + k0),
                                       (lv_t*)&Bs[rb * 64], 16, 0, 0);
    }
    __syncthreads();
#pragma unroll
    for (int s = 0; s < 2; s++) {
      bf16x8 af[4], bfr[4];
      const int slot = ((s * 4 + quad) ^ rsl) * 8;
#pragma unroll
      for (int t = 0; t < 4; t++) {
        af[t]  = *(const bf16x8*)&As[(wm + t * 16 + lane15) * 64 + slot];
        bfr[t] = *(const bf16x8*)&Bs[(wn + t * 16 + lane15) * 64 + slot];
      }
#pragma unroll
      for (int i = 0; i < 4; i++)
#pragma unroll
        for (int j = 0; j < 4; j++)
          acc[i][j] = __builtin_amdgcn_mfma_f32_16x16x32_bf16(af[i], bfr[j], acc[i][j], 0, 0, 0);
    }
  }

  if (MODE == 0) {
    if (n0 >= 2048) {
      // V block: write transposed to vT (tok-major -> one 8B store per (i,j))
#pragma unroll
      for (int i = 0; i < 4; i++) {
        int rowb = m0 + wm + i * 16 + quad * 4;
        int bb = rowb >> 11, t = rowb & 2047;
#pragma unroll
        for (int j = 0; j < 4; j++) {
          int hd = n0 + wn + j * 16 + lane15 - 2048;
          unsigned short* vp = vTout +
              ((size_t)((bb << 4) + (hd >> 6)) * 64 + (hd & 63)) * SEQ + t;
          *(uint2*)vp = make_uint2(rne2(acc[i][j][0], acc[i][j][1]),
                                   rne2(acc[i][j][2], acc[i][j][3]));
        }
      }
    } else {
      unsigned short* Cp = (unsigned short*)Cout;
      const float s = (n0 < 1024) ? 0.18033688f : 1.0f;  // 0.125 * log2(e)
#pragma unroll
      for (int i = 0; i < 4; i++) {
        int rowb = m0 + wm + i * 16 + quad * 4;
#pragma unroll
        for (int j = 0; j < 4; j++) {
          int col = n0 + wn + j * 16 + lane15;
#pragma unroll
          for (int r = 0; r < 4; r++)
            Cp[(size_t)(rowb + r) * N + col] = f2bf(acc[i][j][r] * s);
        }
      }
    }
  } else {
    float* Cp = (float*)Cout;
#pragma unroll
    for (int i = 0; i < 4; i++) {
      int rowb = m0 + wm + i * 16 + quad * 4;
#pragma unroll
      for (int j = 0; j < 4; j++) {
        int col = n0 + wn + j * 16 + lane15;
        float bv = bias[col];
#pragma unroll
        for (int r = 0; r < 4; r++)
          Cp[(size_t)(rowb + r) * N + col] = acc[i][j][r] + bv;
      }
    }
  }
}

// ---------------- flash attention ----------------
// Round-5 structure: causal pairing + K-ONLY LDS double-buffer, V direct
// from global (L2-resident: V panel per head = 256 KB, reused by the 8
// q-pair blocks of that head; LDS V-staging was pure overhead — guide
// common-mistake #7).
//  * LDS 64->32 KB, regs ~160 unified -> 3 blocks/CU (was 2): 1.5x
//    latency-hiding capacity. launch_bounds(256,3).
//  * V fragment address swizzle-free: the stage/read XORs cancel ->
//    vT[(bh*64+row)*SEQ + k0 + (2kk+hl)*8]. 4 loads per subtile cover 128
//    consecutive bytes per row across the unroll (full-line L2 use).
//  * V loads issue right after QK MFMA, consumed after softmax (~200 cy
//    later); compiler inserts exact counted vmcnt waits. Top-of-loop
//    vmcnt(0) only ever waits the 4 K-stage loads.
//  * Same K-order/math as round-4 -> bitwise-identical output.

static __device__ __forceinline__ void stage_k(
    unsigned short* Kb, const unsigned short* __restrict__ qkv,
    size_t tokb, int h, int k0, int w, int krow_l, int kslot)
{
#pragma unroll
  for (int i = 0; i < 4; i++) {
    int rb = (w * 4 + i) * 8;
    int row = rb + krow_l;
    int ck = kslot ^ (row & 7);
    const unsigned short* g = qkv + (tokb + k0 + row) * C3 + C1 + h * 64 + ck * 8;
    __builtin_amdgcn_global_load_lds((gv_t*)g, (lv_t*)&Kb[rb * 64], 16, 0, 0);
  }
}

// one 128-key tile for one q-tile: S^T=K@Q^T -> exp2 -> O^T += V^T@P^T
static __device__ __forceinline__ void attn_tile(
    f32x16* O, float& lrun, const bf16x8* qf,
    const unsigned short* Kb, const unsigned short* __restrict__ vTb,
    bool diag, int k0, int qmy, int w, int l31, int hl)
{
#pragma unroll
  for (int ht = 0; ht < 2; ht++) {
    if (diag && (ht * 2 > w)) continue;     // whole half beyond diagonal
    const bool two = !diag || (ht * 2 + 1 <= w);

#pragma unroll
    for (int lm = 0; lm < 2; lm++) {        // one 32-key sub-tile end-to-end
      if (lm == 1 && !two) continue;
      const int mt = ht * 2 + lm;

      // S^T = K @ Q^T : C[key][q]; acc init -16 = softmax shift
      f32x16 stL;
#pragma unroll
      for (int i = 0; i < 16; i++) stL[i] = -16.f;
      {
        int row = mt * 32 + l31;
        const unsigned short* kr = &Kb[row * 64];
        __builtin_amdgcn_s_setprio(1);
#pragma unroll
        for (int ks = 0; ks < 4; ks++) {
          bf16x8 a = *(const bf16x8*)&kr[((((ks << 1) | hl)) ^ (row & 7)) * 8];
          stL = __builtin_amdgcn_mfma_f32_32x32x16_bf16(a, qf[ks], stL, 0, 0, 0);
        }
        __builtin_amdgcn_s_setprio(0);
      }

      // V fragments direct from global (issued early; consumed after softmax)
      bf16x8 vf[2][2];
#pragma unroll
      for (int e = 0; e < 2; e++) {
        int kk = ht * 4 + lm * 2 + e;
#pragma unroll
        for (int dt = 0; dt < 2; dt++) {
          int row = dt * 32 + l31;
          vf[e][dt] = *(const bf16x8*)&vTb[(size_t)row * SEQ + k0 + (2 * kk + hl) * 8];
        }
      }

      if (diag && mt == w) {  // partial mask (compile-time index, runtime compare)
#pragma unroll
        for (int r = 0; r < 16; r++) {
          int key = k0 + w * 32 + (r & 3) + ((r >> 2) << 3) + (hl << 2);
          if (key > qmy) stL[r] = -1e30f;
        }
      }

      // fixed-max softmax: P = exp2(S - 16); psum via 4 parallel accumulators
      float ps0 = 0.f, ps1 = 0.f, ps2 = 0.f, ps3 = 0.f;
      unsigned pk[8];
#pragma unroll
      for (int r = 0; r < 16; r += 4) {
        float p0 = EXP2(stL[r]);
        float p1 = EXP2(stL[r + 1]);
        float p2 = EXP2(stL[r + 2]);
        float p3 = EXP2(stL[r + 3]);
        ps0 += p0; ps1 += p1; ps2 += p2; ps3 += p3;
        pk[(r >> 1)]     = pk2(p0, p1);
        pk[(r >> 1) + 1] = pk2(p2, p3);
      }
      lrun += (ps0 + ps1) + (ps2 + ps3);

      // O^T += V^T @ P^T (2 ksteps of 16 keys); permlane32_swap builds B-frag
#pragma unroll
      for (int e = 0; e < 2; e++) {
        union { unsigned u[4]; bf16x8 v; } Bf;
        plswap(pk[4 * e],     pk[4 * e + 2], Bf.u[0], Bf.u[2]);
        plswap(pk[4 * e + 1], pk[4 * e + 3], Bf.u[1], Bf.u[3]);
        __builtin_amdgcn_s_setprio(1);
        O[0] = __builtin_amdgcn_mfma_f32_32x32x16_bf16(vf[e][0], Bf.v, O[0], 0, 0, 0);
        O[1] = __builtin_amdgcn_mfma_f32_32x32x16_bf16(vf[e][1], Bf.v, O[1], 0, 0, 0);
        __builtin_amdgcn_s_setprio(0);
      }
    }
  }
}

// epilogue: O^T (C-layout) -> LDS [q][d] -> coalesced bf16 store
static __device__ __forceinline__ void attn_epi(
    const f32x16* O, float lrun, unsigned short* buf,
    unsigned short* __restrict__ att, size_t tokb, int q0, int h,
    int w, int l, int l31, int hl)
{
  lrun += __shfl_xor(lrun, 32, 64);  // combine q halves
  float linv = __builtin_amdgcn_rcpf(lrun);
  unsigned* epi32 = (unsigned*)buf;
  const int base = w * 2304 + l31 * 72;
  __builtin_amdgcn_s_waitcnt(0);  // prior reads of this LDS region retired
#pragma unroll
  for (int dt = 0; dt < 2; dt++)
#pragma unroll
    for (int c = 0; c < 4; c++) {
      int d0 = dt * 32 + c * 8 + hl * 4;
      epi32[(base + d0) >> 1]     = rne2(O[dt][4 * c] * linv, O[dt][4 * c + 1] * linv);
      epi32[(base + d0 + 2) >> 1] = rne2(O[dt][4 * c + 2] * linv, O[dt][4 * c + 3] * linv);
    }
  __builtin_amdgcn_s_waitcnt(0);  // lgkm drain before cross-lane read (same wave)
  {
    int q = l >> 1, hf = l & 1;
    const unsigned short* ep = &buf[w * 2304 + q * 72 + hf * 32];
    unsigned short* og = att + (tokb + q0 + w * 32 + q) * C1 + h * 64 + hf * 32;
#pragma unroll
    for (int c2 = 0; c2 < 4; c2++)
      *(bf16x8*)(og + c2 * 8) = *(const bf16x8*)&ep[c2 * 8];
  }
}

__global__ __launch_bounds__(256, 3) void k_attn(
    const unsigned short* __restrict__ qkv, const unsigned short* __restrict__ vT,
    unsigned short* __restrict__ att)
{
  __shared__ unsigned short buf[2][8192];  // per buf: K 128x64 (16 KB)
  const int tid = threadIdx.x;
  const int w = tid >> 6, l = tid & 63;
  const int l31 = l & 31, hl = l >> 5;
  const int bh = blockIdx.x, b = bh >> 4, h = bh & 15;
  const int yq = blockIdx.y;                // 0..7
  const int qt_lo = yq, qt_hi = 15 - yq;    // paired q-tiles: uniform work 17
  const int q0l = qt_lo << 7, q0h = qt_hi << 7;
  const int nkt = qt_hi + 1;
  const size_t tokb = (size_t)b * SEQ;
  const int qmy_l = q0l + w * 32 + l31;
  const int qmy_h = q0h + w * 32 + l31;

  const int krow_l = l >> 3, kslot = l & 7;
  const unsigned short* vTb = vT + (size_t)bh * 64 * SEQ;

  // Q B-frags (global, once per q-tile): B[k=d][n=q], k = hl*8+j within kstep
  bf16x8 qfh[4], qfl[4];
  {
    const unsigned short* qph = qkv + (tokb + q0h + w * 32 + l31) * C3 + h * 64 + hl * 8;
    const unsigned short* qpl = qkv + (tokb + q0l + w * 32 + l31) * C3 + h * 64 + hl * 8;
#pragma unroll
    for (int ks = 0; ks < 4; ks++) {
      qfh[ks] = *(const bf16x8*)(qph + ks * 16);
      qfl[ks] = *(const bf16x8*)(qpl + ks * 16);
    }
  }

  f32x16 Oh[2], Ol[2];
#pragma unroll
  for (int i = 0; i < 16; i++) { Oh[0][i] = 0.f; Oh[1][i] = 0.f; Ol[0][i] = 0.f; Ol[1][i] = 0.f; }
  float lrh = 0.f, lrl = 0.f;

  // prologue: stage K tile 0
  stage_k(&buf[0][0], qkv, tokb, h, 0, w, krow_l, kslot);

  int cur = 0;
  for (int kt = 0; kt < nkt; kt++) {
    asm volatile("s_waitcnt vmcnt(0)" ::: "memory");  // own K-stage of buf[cur] landed
    __builtin_amdgcn_s_barrier();                      // everyone's landed; prev reads done
    if (kt + 1 < nkt)
      stage_k(&buf[cur ^ 1][0], qkv, tokb, h, (kt + 1) << 7, w, krow_l, kslot);

    const unsigned short* Kb = &buf[cur][0];
    const int k0 = kt << 7;

    attn_tile(Oh, lrh, qfh, Kb, vTb, kt == qt_hi, k0, qmy_h, w, l31, hl);
    if (kt <= qt_lo)
      attn_tile(Ol, lrl, qfl, Kb, vTb, kt == qt_lo, k0, qmy_l, w, l31, hl);

    cur ^= 1;
  }

  __syncthreads();  // all waves done reading buf before epilogue overlay
  attn_epi(Oh, lrh, &buf[0][0], att, tokb, q0h, h, w, l, l31, hl);
  attn_epi(Ol, lrl, &buf[0][0], att, tokb, q0l, h, w, l, l31, hl);
}

extern "C" void kernel_launch(void* const* d_in, const int* in_sizes, int n_in,
                              void* d_out, int out_size, void* d_ws, size_t ws_size,
                              hipStream_t stream) {
  const float* x     = (const float*)d_in[0];
  const float* w_qkv = (const float*)d_in[1];
  const float* w_out = (const float*)d_in[2];
  const float* b_out = (const float*)d_in[3];
  float* out = (float*)d_out;

  unsigned short* xb  = (unsigned short*)d_ws;
  unsigned short* wqb = xb  + (size_t)8192 * 1024;
  unsigned short* wob = wqb + (size_t)3072 * 1024;
  unsigned short* qkv = wob + (size_t)1024 * 1024;
  unsigned short* att = qkv + (size_t)8192 * 3072;
  unsigned short* vT  = att + (size_t)8192 * 1024;

  k_cvt3<<<12288, 256, 0, stream>>>(x, w_qkv, w_out, xb, wqb, wob);
  k_gemm<0><<<dim3(24, 64), 256, 0, stream>>>(xb, wqb, (void*)qkv, nullptr, vT, 8192, 3072, 1024);
  k_attn<<<dim3(64, 8), 256, 0, stream>>>(qkv, vT, att);
  k_gemm<1><<<dim3(8, 64), 256, 0, stream>>>(att, wob, (void*)out, b_out, nullptr, 8192, 1024, 1024);
}

// Round 6
// 257.545 us; speedup vs baseline: 1.1146x; 1.1146x over previous
//
#include <hip/hip_runtime.h>
#include <stdint.h>

#define SEQ 2048
#define C3 3072
#define C1 1024

typedef __bf16 bf16x8 __attribute__((ext_vector_type(8)));
typedef short short8 __attribute__((ext_vector_type(8)));
typedef float f32x4 __attribute__((ext_vector_type(4)));
typedef float f32x16 __attribute__((ext_vector_type(16)));
typedef unsigned uintx2 __attribute__((ext_vector_type(2)));
typedef const __attribute__((address_space(1))) void gv_t;
typedef __attribute__((address_space(3))) void lv_t;

#if __has_builtin(__builtin_amdgcn_exp2f)
#define EXP2(x) __builtin_amdgcn_exp2f(x)
#else
#define EXP2(x) exp2f(x)
#endif

static __device__ __forceinline__ unsigned short f2bf(float f) {
  union { float ff; unsigned u; } x; x.ff = f;
  unsigned u = x.u + 0x7FFFu + ((x.u >> 16) & 1u);
  return (unsigned short)(u >> 16);
}
static __device__ __forceinline__ unsigned rne2(float lo, float hi) {
  return (unsigned)f2bf(lo) | ((unsigned)f2bf(hi) << 16);
}
// pack top halves of two f32 -> one bf16x2 dword (truncation; P in [0,1])
static __device__ __forceinline__ unsigned pk2(float lo, float hi) {
  union { float f; unsigned u; } a, b; a.f = lo; b.f = hi;
  return __builtin_amdgcn_perm(b.u, a.u, 0x07060302);
}

// v_permlane32_swap_b32: vdst upper 32 lanes <-> src lower 32 lanes.
// out0[l] = l<32 ? a[l] : b[l-32];  out1[l] = l<32 ? a[l+32] : b[l]
static __device__ __forceinline__ void plswap(unsigned a, unsigned b,
                                              unsigned& o0, unsigned& o1) {
#if __has_builtin(__builtin_amdgcn_permlane32_swap)
  uintx2 r = __builtin_amdgcn_permlane32_swap(a, b, false, false);
  o0 = r[0]; o1 = r[1];
#else
  asm volatile("v_permlane32_swap_b32 %0, %1" : "+v"(a), "+v"(b));
  o0 = a; o1 = b;
#endif
}

// fused fp32->bf16 convert for x | w_qkv | w_out; 4 f32x4 per thread
// (grid 3072 = 2048 x | 768 wqkv | 256 wout blocks of 1024 f32x4 each)
__global__ void k_cvt3(const float* __restrict__ ia, const float* __restrict__ ib,
                       const float* __restrict__ ic, unsigned short* __restrict__ oa,
                       unsigned short* __restrict__ ob, unsigned short* __restrict__ oc) {
  int blk = blockIdx.x;
  const float* in; unsigned short* out; int base;
  if (blk < 2048)     { in = ia; out = oa; base = blk; }
  else if (blk < 2816){ in = ib; out = ob; base = blk - 2048; }
  else                { in = ic; out = oc; base = blk - 2816; }
  int i0 = base * 1024 + threadIdx.x;
#pragma unroll
  for (int j = 0; j < 4; j++) {
    int i = i0 + j * 256;
    f32x4 v = ((const f32x4*)in)[i];
    ushort4 o;
    o.x = f2bf(v[0]); o.y = f2bf(v[1]); o.z = f2bf(v[2]); o.w = f2bf(v[3]);
    ((ushort4*)out)[i] = o;
  }
}

// C[M,N] = A[M,K] @ B[N,K]^T, bf16 in, BK=64.
// MODE 0: bf16 out; cols<1024 scaled by 0.125*log2(e) (Q prescale); V columns
// (n0>=2048, block-uniform) written TRANSPOSED to vTout[(b*16+h)*64+d][tok].
// MODE 1: f32 out + bias.
// (Round-3 tried T1 XCD swizzle: regressed 58.4->62.4, FETCH up — inputs are
// L3-resident so swizzle only hurt; reverted per m160's "costs ~2% when L3-fit".)
template<int MODE>
__global__ __launch_bounds__(256, 3) void k_gemm(
    const unsigned short* __restrict__ A, const unsigned short* __restrict__ B,
    void* __restrict__ Cout, const float* __restrict__ bias,
    unsigned short* __restrict__ vTout, int M, int N, int K)
{
  __shared__ unsigned short As[128 * 64];
  __shared__ unsigned short Bs[128 * 64];
  const int tid = threadIdx.x;
  const int w = tid >> 6, l = tid & 63;
  const int lane15 = l & 15, quad = l >> 4;
  const int m0 = blockIdx.y * 128, n0 = blockIdx.x * 128;
  const int wm = (w >> 1) * 64, wn = (w & 1) * 64;

  f32x4 acc[4][4];
#pragma unroll
  for (int i = 0; i < 4; i++)
#pragma unroll
    for (int j = 0; j < 4; j++) acc[i][j] = (f32x4){0.f, 0.f, 0.f, 0.f};

  const int srow = l >> 3;
  const int g_off = ((l & 7) ^ (srow & 7)) * 8;
  const unsigned short* Ab = A + (size_t)(m0 + w * 32 + srow) * K + g_off;
  const unsigned short* Bb = B + (size_t)(n0 + w * 32 + srow) * K + g_off;
  const int rsl = lane15 & 7;

  for (int k0 = 0; k0 < K; k0 += 64) {
    __syncthreads();
#pragma unroll
    for (int i = 0; i < 4; i++) {
      int rb = w * 32 + i * 8;
      __builtin_amdgcn_global_load_lds((gv_t*)(Ab + (size_t)(i * 8) * K + k0),
                                       (lv_t*)&As[rb * 64], 16, 0, 0);
      __builtin_amdgcn_global_load_lds((gv_t*)(Bb + (size_t)(i * 8) * K + k0),
                                       (lv_t*)&Bs[rb * 64], 16, 0, 0);
    }
    __syncthreads();
#pragma unroll
    for (int s = 0; s < 2; s++) {
      bf16x8 af[4], bfr[4];
      const int slot = ((s * 4 + quad) ^ rsl) * 8;
#pragma unroll
      for (int t = 0; t < 4; t++) {
        af[t]  = *(const bf16x8*)&As[(wm + t * 16 + lane15) * 64 + slot];
        bfr[t] = *(const bf16x8*)&Bs[(wn + t * 16 + lane15) * 64 + slot];
      }
#pragma unroll
      for (int i = 0; i < 4; i++)
#pragma unroll
        for (int j = 0; j < 4; j++)
          acc[i][j] = __builtin_amdgcn_mfma_f32_16x16x32_bf16(af[i], bfr[j], acc[i][j], 0, 0, 0);
    }
  }

  if (MODE == 0) {
    if (n0 >= 2048) {
      // V block: write transposed to vT (tok-major -> one 8B store per (i,j))
#pragma unroll
      for (int i = 0; i < 4; i++) {
        int rowb = m0 + wm + i * 16 + quad * 4;
        int bb = rowb >> 11, t = rowb & 2047;
#pragma unroll
        for (int j = 0; j < 4; j++) {
          int hd = n0 + wn + j * 16 + lane15 - 2048;
          unsigned short* vp = vTout +
              ((size_t)((bb << 4) + (hd >> 6)) * 64 + (hd & 63)) * SEQ + t;
          *(uint2*)vp = make_uint2(rne2(acc[i][j][0], acc[i][j][1]),
                                   rne2(acc[i][j][2], acc[i][j][3]));
        }
      }
    } else {
      unsigned short* Cp = (unsigned short*)Cout;
      const float s = (n0 < 1024) ? 0.18033688f : 1.0f;  // 0.125 * log2(e)
#pragma unroll
      for (int i = 0; i < 4; i++) {
        int rowb = m0 + wm + i * 16 + quad * 4;
#pragma unroll
        for (int j = 0; j < 4; j++) {
          int col = n0 + wn + j * 16 + lane15;
#pragma unroll
          for (int r = 0; r < 4; r++)
            Cp[(size_t)(rowb + r) * N + col] = f2bf(acc[i][j][r] * s);
        }
      }
    }
  } else {
    float* Cp = (float*)Cout;
#pragma unroll
    for (int i = 0; i < 4; i++) {
      int rowb = m0 + wm + i * 16 + quad * 4;
#pragma unroll
      for (int j = 0; j < 4; j++) {
        int col = n0 + wn + j * 16 + lane15;
        float bv = bias[col];
#pragma unroll
        for (int r = 0; r < 4; r++)
          Cp[(size_t)(rowb + r) * N + col] = acc[i][j][r] + bv;
      }
    }
  }
}

// ---------------- flash attention ----------------
// Round-6: round-4 compute path EXACTLY (V via LDS [64][128], same swizzles,
// same K-order -> bitwise-identical output), staging schedule changed:
//  * K double-buffered (2x16 KB), staged EARLY (after barrier A) — hidden
//    under tile compute, as before.
//  * V SINGLE buffer (16 KB), staged LATE (after barrier B at tile end, when
//    all waves' V(t) ds_reads have executed). Its latency sits in the
//    vmcnt(0) before barrier A — exposed per block, covered cross-block.
//  * LDS 64 -> 48 KB => 3 blocks/CU (regs ~148 unified <= 170 at (256,3));
//    1.5x latency-hiding capacity is the point of the trade.
// (Round-5's V-direct-from-global failed on coalescing: 4 KB lane stride =
// 64 lines per load instruction -> VMEM serialization, 121 us. Reverted.)

static __device__ __forceinline__ void stage_k(
    unsigned short* Kb, const unsigned short* __restrict__ qkv,
    size_t tokb, int h, int k0, int w, int krow_l, int kslot)
{
#pragma unroll
  for (int i = 0; i < 4; i++) {
    int rb = (w * 4 + i) * 8;
    int row = rb + krow_l;
    int ck = kslot ^ (row & 7);
    const unsigned short* g = qkv + (tokb + k0 + row) * C3 + C1 + h * 64 + ck * 8;
    __builtin_amdgcn_global_load_lds((gv_t*)g, (lv_t*)&Kb[rb * 64], 16, 0, 0);
  }
}

static __device__ __forceinline__ void stage_v(
    unsigned short* Vb, const unsigned short* __restrict__ vT,
    int bh, int k0, int w, int vrow_l, int vslot)
{
#pragma unroll
  for (int i = 0; i < 4; i++) {
    int rb = (w * 4 + i) * 4;
    int row = rb + vrow_l;
    int ck = vslot ^ (row & 15);
    const unsigned short* g = vT + ((size_t)bh * 64 + row) * SEQ + k0 + ck * 8;
    __builtin_amdgcn_global_load_lds((gv_t*)g, (lv_t*)&Vb[rb * 128], 16, 0, 0);
  }
}

// one 128-key tile for one q-tile: S^T=K@Q^T -> exp2 -> O^T += V^T@P^T
static __device__ __forceinline__ void attn_tile(
    f32x16* O, float& lrun, const bf16x8* qf,
    const unsigned short* Kb, const unsigned short* Vb,
    bool diag, int k0, int qmy, int w, int l31, int hl)
{
#pragma unroll
  for (int ht = 0; ht < 2; ht++) {
    if (diag && (ht * 2 > w)) continue;     // whole half beyond diagonal
    const bool two = !diag || (ht * 2 + 1 <= w);

#pragma unroll
    for (int lm = 0; lm < 2; lm++) {        // one 32-key sub-tile end-to-end
      if (lm == 1 && !two) continue;
      const int mt = ht * 2 + lm;

      // S^T = K @ Q^T : C[key][q]; acc init -16 = softmax shift
      f32x16 stL;
#pragma unroll
      for (int i = 0; i < 16; i++) stL[i] = -16.f;
      {
        int row = mt * 32 + l31;
        const unsigned short* kr = &Kb[row * 64];
        __builtin_amdgcn_s_setprio(1);
#pragma unroll
        for (int ks = 0; ks < 4; ks++) {
          bf16x8 a = *(const bf16x8*)&kr[((((ks << 1) | hl)) ^ (row & 7)) * 8];
          stL = __builtin_amdgcn_mfma_f32_32x32x16_bf16(a, qf[ks], stL, 0, 0, 0);
        }
        __builtin_amdgcn_s_setprio(0);
      }

      if (diag && mt == w) {  // partial mask (compile-time index, runtime compare)
#pragma unroll
        for (int r = 0; r < 16; r++) {
          int key = k0 + w * 32 + (r & 3) + ((r >> 2) << 3) + (hl << 2);
          if (key > qmy) stL[r] = -1e30f;
        }
      }

      // fixed-max softmax: P = exp2(S - 16); psum via 4 parallel accumulators
      float ps0 = 0.f, ps1 = 0.f, ps2 = 0.f, ps3 = 0.f;
      unsigned pk[8];
#pragma unroll
      for (int r = 0; r < 16; r += 4) {
        float p0 = EXP2(stL[r]);
        float p1 = EXP2(stL[r + 1]);
        float p2 = EXP2(stL[r + 2]);
        float p3 = EXP2(stL[r + 3]);
        ps0 += p0; ps1 += p1; ps2 += p2; ps3 += p3;
        pk[(r >> 1)]     = pk2(p0, p1);
        pk[(r >> 1) + 1] = pk2(p2, p3);
      }
      lrun += (ps0 + ps1) + (ps2 + ps3);

      // V fragments batched upfront (one LDS latency hop, not four)
      bf16x8 vf[2][2];
#pragma unroll
      for (int e = 0; e < 2; e++) {
        int kk = ht * 4 + lm * 2 + e;
#pragma unroll
        for (int dt = 0; dt < 2; dt++) {
          int row = dt * 32 + l31;
          vf[e][dt] = *(const bf16x8*)&Vb[row * 128 + (((2 * kk + hl)) ^ (row & 15)) * 8];
        }
      }

      // O^T += V^T @ P^T (2 ksteps of 16 keys); permlane32_swap builds B-frag
#pragma unroll
      for (int e = 0; e < 2; e++) {
        union { unsigned u[4]; bf16x8 v; } Bf;
        plswap(pk[4 * e],     pk[4 * e + 2], Bf.u[0], Bf.u[2]);
        plswap(pk[4 * e + 1], pk[4 * e + 3], Bf.u[1], Bf.u[3]);
        __builtin_amdgcn_s_setprio(1);
        O[0] = __builtin_amdgcn_mfma_f32_32x32x16_bf16(vf[e][0], Bf.v, O[0], 0, 0, 0);
        O[1] = __builtin_amdgcn_mfma_f32_32x32x16_bf16(vf[e][1], Bf.v, O[1], 0, 0, 0);
        __builtin_amdgcn_s_setprio(0);
      }
    }
  }
}

// epilogue: O^T (C-layout) -> LDS [q][d] -> coalesced bf16 store
static __device__ __forceinline__ void attn_epi(
    const f32x16* O, float lrun, unsigned short* buf,
    unsigned short* __restrict__ att, size_t tokb, int q0, int h,
    int w, int l, int l31, int hl)
{
  lrun += __shfl_xor(lrun, 32, 64);  // combine q halves
  float linv = __builtin_amdgcn_rcpf(lrun);
  unsigned* epi32 = (unsigned*)buf;
  const int base = w * 2304 + l31 * 72;
  __builtin_amdgcn_s_waitcnt(0);  // prior reads of this LDS region retired
#pragma unroll
  for (int dt = 0; dt < 2; dt++)
#pragma unroll
    for (int c = 0; c < 4; c++) {
      int d0 = dt * 32 + c * 8 + hl * 4;
      epi32[(base + d0) >> 1]     = rne2(O[dt][4 * c] * linv, O[dt][4 * c + 1] * linv);
      epi32[(base + d0 + 2) >> 1] = rne2(O[dt][4 * c + 2] * linv, O[dt][4 * c + 3] * linv);
    }
  __builtin_amdgcn_s_waitcnt(0);  // lgkm drain before cross-lane read (same wave)
  {
    int q = l >> 1, hf = l & 1;
    const unsigned short* ep = &buf[w * 2304 + q * 72 + hf * 32];
    unsigned short* og = att + (tokb + q0 + w * 32 + q) * C1 + h * 64 + hf * 32;
#pragma unroll
    for (int c2 = 0; c2 < 4; c2++)
      *(bf16x8*)(og + c2 * 8) = *(const bf16x8*)&ep[c2 * 8];
  }
}

__global__ __launch_bounds__(256, 3) void k_attn(
    const unsigned short* __restrict__ qkv, const unsigned short* __restrict__ vT,
    unsigned short* __restrict__ att)
{
  __shared__ unsigned short bufK[2][8192];  // K 128x64 double-buffered
  __shared__ unsigned short bufV[8192];     // Vt 64x128 single buffer
  const int tid = threadIdx.x;
  const int w = tid >> 6, l = tid & 63;
  const int l31 = l & 31, hl = l >> 5;
  const int bh = blockIdx.x, b = bh >> 4, h = bh & 15;
  const int yq = blockIdx.y;                // 0..7
  const int qt_lo = yq, qt_hi = 15 - yq;    // paired q-tiles: uniform work 17
  const int q0l = qt_lo << 7, q0h = qt_hi << 7;
  const int nkt = qt_hi + 1;
  const size_t tokb = (size_t)b * SEQ;
  const int qmy_l = q0l + w * 32 + l31;
  const int qmy_h = q0h + w * 32 + l31;

  const int krow_l = l >> 3, kslot = l & 7;
  const int vrow_l = l >> 4, vslot = l & 15;

  // Q B-frags (global, once per q-tile): B[k=d][n=q], k = hl*8+j within kstep
  bf16x8 qfh[4], qfl[4];
  {
    const unsigned short* qph = qkv + (tokb + q0h + w * 32 + l31) * C3 + h * 64 + hl * 8;
    const unsigned short* qpl = qkv + (tokb + q0l + w * 32 + l31) * C3 + h * 64 + hl * 8;
#pragma unroll
    for (int ks = 0; ks < 4; ks++) {
      qfh[ks] = *(const bf16x8*)(qph + ks * 16);
      qfl[ks] = *(const bf16x8*)(qpl + ks * 16);
    }
  }

  f32x16 Oh[2], Ol[2];
#pragma unroll
  for (int i = 0; i < 16; i++) { Oh[0][i] = 0.f; Oh[1][i] = 0.f; Ol[0][i] = 0.f; Ol[1][i] = 0.f; }
  float lrh = 0.f, lrl = 0.f;

  // prologue: stage K+V of tile 0
  stage_k(&bufK[0][0], qkv, tokb, h, 0, w, krow_l, kslot);
  stage_v(&bufV[0], vT, bh, 0, w, vrow_l, vslot);

  int cur = 0;
  for (int kt = 0; kt < nkt; kt++) {
    asm volatile("s_waitcnt vmcnt(0)" ::: "memory");  // own K/V stages landed
    __builtin_amdgcn_s_barrier();                      // A: everyone's landed
    if (kt + 1 < nkt)
      stage_k(&bufK[cur ^ 1][0], qkv, tokb, h, (kt + 1) << 7, w, krow_l, kslot);

    const unsigned short* Kb = &bufK[cur][0];
    const int k0 = kt << 7;

    attn_tile(Oh, lrh, qfh, Kb, bufV, kt == qt_hi, k0, qmy_h, w, l31, hl);
    if (kt <= qt_lo)
      attn_tile(Ol, lrl, qfl, Kb, bufV, kt == qt_lo, k0, qmy_l, w, l31, hl);

    __builtin_amdgcn_s_barrier();                      // B: all V(kt) reads done
    if (kt + 1 < nkt)
      stage_v(&bufV[0], vT, bh, (kt + 1) << 7, w, vrow_l, vslot);

    cur ^= 1;
  }

  __syncthreads();  // all waves done before epilogue overlay of bufK
  attn_epi(Oh, lrh, &bufK[0][0], att, tokb, q0h, h, w, l, l31, hl);
  attn_epi(Ol, lrl, &bufK[0][0], att, tokb, q0l, h, w, l, l31, hl);
}

extern "C" void kernel_launch(void* const* d_in, const int* in_sizes, int n_in,
                              void* d_out, int out_size, void* d_ws, size_t ws_size,
                              hipStream_t stream) {
  const float* x     = (const float*)d_in[0];
  const float* w_qkv = (const float*)d_in[1];
  const float* w_out = (const float*)d_in[2];
  const float* b_out = (const float*)d_in[3];
  float* out = (float*)d_out;

  unsigned short* xb  = (unsigned short*)d_ws;
  unsigned short* wqb = xb  + (size_t)8192 * 1024;
  unsigned short* wob = wqb + (size_t)3072 * 1024;
  unsigned short* qkv = wob + (size_t)1024 * 1024;
  unsigned short* att = qkv + (size_t)8192 * 3072;
  unsigned short* vT  = att + (size_t)8192 * 1024;

  k_cvt3<<<3072, 256, 0, stream>>>(x, w_qkv, w_out, xb, wqb, wob);
  k_gemm<0><<<dim3(24, 64), 256, 0, stream>>>(xb, wqb, (void*)qkv, nullptr, vT, 8192, 3072, 1024);
  k_attn<<<dim3(64, 8), 256, 0, stream>>>(qkv, vT, att);
  k_gemm<1><<<dim3(8, 64), 256, 0, stream>>>(att, wob, (void*)out, b_out, nullptr, 8192, 1024, 1024);
}

// Round 7
// 229.463 us; speedup vs baseline: 1.2510x; 1.1224x over previous
//
#include <hip/hip_runtime.h>
#include <stdint.h>

#define SEQ 2048
#define C3 3072
#define C1 1024

typedef __bf16 bf16x8 __attribute__((ext_vector_type(8)));
typedef short short8 __attribute__((ext_vector_type(8)));
typedef float f32x4 __attribute__((ext_vector_type(4)));
typedef float f32x16 __attribute__((ext_vector_type(16)));
typedef unsigned uintx2 __attribute__((ext_vector_type(2)));
typedef const __attribute__((address_space(1))) void gv_t;
typedef __attribute__((address_space(3))) void lv_t;

#if __has_builtin(__builtin_amdgcn_exp2f)
#define EXP2(x) __builtin_amdgcn_exp2f(x)
#else
#define EXP2(x) exp2f(x)
#endif

static __device__ __forceinline__ unsigned short f2bf(float f) {
  union { float ff; unsigned u; } x; x.ff = f;
  unsigned u = x.u + 0x7FFFu + ((x.u >> 16) & 1u);
  return (unsigned short)(u >> 16);
}
static __device__ __forceinline__ unsigned rne2(float lo, float hi) {
  return (unsigned)f2bf(lo) | ((unsigned)f2bf(hi) << 16);
}
// pack top halves of two f32 -> one bf16x2 dword (truncation; P in [0,1])
static __device__ __forceinline__ unsigned pk2(float lo, float hi) {
  union { float f; unsigned u; } a, b; a.f = lo; b.f = hi;
  return __builtin_amdgcn_perm(b.u, a.u, 0x07060302);
}

// v_permlane32_swap_b32: vdst upper 32 lanes <-> src lower 32 lanes.
// out0[l] = l<32 ? a[l] : b[l-32];  out1[l] = l<32 ? a[l+32] : b[l]
static __device__ __forceinline__ void plswap(unsigned a, unsigned b,
                                              unsigned& o0, unsigned& o1) {
#if __has_builtin(__builtin_amdgcn_permlane32_swap)
  uintx2 r = __builtin_amdgcn_permlane32_swap(a, b, false, false);
  o0 = r[0]; o1 = r[1];
#else
  asm volatile("v_permlane32_swap_b32 %0, %1" : "+v"(a), "+v"(b));
  o0 = a; o1 = b;
#endif
}

// fused fp32->bf16 convert for x | w_qkv | w_out; 4 f32x4 per thread
// (grid 3072 = 2048 x | 768 wqkv | 256 wout blocks of 1024 f32x4 each)
__global__ void k_cvt3(const float* __restrict__ ia, const float* __restrict__ ib,
                       const float* __restrict__ ic, unsigned short* __restrict__ oa,
                       unsigned short* __restrict__ ob, unsigned short* __restrict__ oc) {
  int blk = blockIdx.x;
  const float* in; unsigned short* out; int base;
  if (blk < 2048)     { in = ia; out = oa; base = blk; }
  else if (blk < 2816){ in = ib; out = ob; base = blk - 2048; }
  else                { in = ic; out = oc; base = blk - 2816; }
  int i0 = base * 1024 + threadIdx.x;
#pragma unroll
  for (int j = 0; j < 4; j++) {
    int i = i0 + j * 256;
    f32x4 v = ((const f32x4*)in)[i];
    ushort4 o;
    o.x = f2bf(v[0]); o.y = f2bf(v[1]); o.z = f2bf(v[2]); o.w = f2bf(v[3]);
    ((ushort4*)out)[i] = o;
  }
}

// C[M,N] = A[M,K] @ B[N,K]^T, bf16 in, BK=64.
// MODE 0: bf16 out; cols<1024 scaled by 0.125*log2(e) (Q prescale); V columns
// (n0>=2048, block-uniform) written TRANSPOSED to vTout[(b*16+h)*64+d][tok].
// MODE 1: f32 out + bias.
// (Round-3 tried T1 XCD swizzle: regressed 58.4->62.4, FETCH up — inputs are
// L3-resident so swizzle only hurt; reverted per m160's "costs ~2% when L3-fit".)
template<int MODE>
__global__ __launch_bounds__(256, 3) void k_gemm(
    const unsigned short* __restrict__ A, const unsigned short* __restrict__ B,
    void* __restrict__ Cout, const float* __restrict__ bias,
    unsigned short* __restrict__ vTout, int M, int N, int K)
{
  __shared__ unsigned short As[128 * 64];
  __shared__ unsigned short Bs[128 * 64];
  const int tid = threadIdx.x;
  const int w = tid >> 6, l = tid & 63;
  const int lane15 = l & 15, quad = l >> 4;
  const int m0 = blockIdx.y * 128, n0 = blockIdx.x * 128;
  const int wm = (w >> 1) * 64, wn = (w & 1) * 64;

  f32x4 acc[4][4];
#pragma unroll
  for (int i = 0; i < 4; i++)
#pragma unroll
    for (int j = 0; j < 4; j++) acc[i][j] = (f32x4){0.f, 0.f, 0.f, 0.f};

  const int srow = l >> 3;
  const int g_off = ((l & 7) ^ (srow & 7)) * 8;
  const unsigned short* Ab = A + (size_t)(m0 + w * 32 + srow) * K + g_off;
  const unsigned short* Bb = B + (size_t)(n0 + w * 32 + srow) * K + g_off;
  const int rsl = lane15 & 7;

  for (int k0 = 0; k0 < K; k0 += 64) {
    __syncthreads();
#pragma unroll
    for (int i = 0; i < 4; i++) {
      int rb = w * 32 + i * 8;
      __builtin_amdgcn_global_load_lds((gv_t*)(Ab + (size_t)(i * 8) * K + k0),
                                       (lv_t*)&As[rb * 64], 16, 0, 0);
      __builtin_amdgcn_global_load_lds((gv_t*)(Bb + (size_t)(i * 8) * K + k0),
                                       (lv_t*)&Bs[rb * 64], 16, 0, 0);
    }
    __syncthreads();
#pragma unroll
    for (int s = 0; s < 2; s++) {
      bf16x8 af[4], bfr[4];
      const int slot = ((s * 4 + quad) ^ rsl) * 8;
#pragma unroll
      for (int t = 0; t < 4; t++) {
        af[t]  = *(const bf16x8*)&As[(wm + t * 16 + lane15) * 64 + slot];
        bfr[t] = *(const bf16x8*)&Bs[(wn + t * 16 + lane15) * 64 + slot];
      }
#pragma unroll
      for (int i = 0; i < 4; i++)
#pragma unroll
        for (int j = 0; j < 4; j++)
          acc[i][j] = __builtin_amdgcn_mfma_f32_16x16x32_bf16(af[i], bfr[j], acc[i][j], 0, 0, 0);
    }
  }

  if (MODE == 0) {
    if (n0 >= 2048) {
      // V block: write transposed to vT (tok-major -> one 8B store per (i,j))
#pragma unroll
      for (int i = 0; i < 4; i++) {
        int rowb = m0 + wm + i * 16 + quad * 4;
        int bb = rowb >> 11, t = rowb & 2047;
#pragma unroll
        for (int j = 0; j < 4; j++) {
          int hd = n0 + wn + j * 16 + lane15 - 2048;
          unsigned short* vp = vTout +
              ((size_t)((bb << 4) + (hd >> 6)) * 64 + (hd & 63)) * SEQ + t;
          *(uint2*)vp = make_uint2(rne2(acc[i][j][0], acc[i][j][1]),
                                   rne2(acc[i][j][2], acc[i][j][3]));
        }
      }
    } else {
      unsigned short* Cp = (unsigned short*)Cout;
      const float s = (n0 < 1024) ? 0.18033688f : 1.0f;  // 0.125 * log2(e)
#pragma unroll
      for (int i = 0; i < 4; i++) {
        int rowb = m0 + wm + i * 16 + quad * 4;
#pragma unroll
        for (int j = 0; j < 4; j++) {
          int col = n0 + wn + j * 16 + lane15;
#pragma unroll
          for (int r = 0; r < 4; r++)
            Cp[(size_t)(rowb + r) * N + col] = f2bf(acc[i][j][r] * s);
        }
      }
    }
  } else {
    float* Cp = (float*)Cout;
#pragma unroll
    for (int i = 0; i < 4; i++) {
      int rowb = m0 + wm + i * 16 + quad * 4;
#pragma unroll
      for (int j = 0; j < 4; j++) {
        int col = n0 + wn + j * 16 + lane15;
        float bv = bias[col];
#pragma unroll
        for (int r = 0; r < 4; r++)
          Cp[(size_t)(rowb + r) * N + col] = acc[i][j][r] + bv;
      }
    }
  }
}

// ---------------- flash attention ----------------
// Round-7: WAVE-SPECIALIZED 512-thread blocks. Same 512-block grid
// (64 bh x 8 pairs), same K/V dbuf LDS (64 KB/block), same compute path and
// K-order as round-4 (bitwise-identical output). Waves 0-3 own the HI
// q-tile, waves 4-7 the LO q-tile; both share each staged K/V tile.
//  * Per-wave state halves (one qf[4], one O[2]) -> ~108 unified regs
//    <= 128 cap of launch_bounds(512,2) -> 2 blocks/CU x 8 waves =
//    4 waves/SIMD during overlap (round-4: 2). Registers, not LDS, were
//    the path to TLP — r2/r5/r6 failed because the 512-block grid caps
//    blocks/CU at 2 regardless of LDS.
//  * hi/lo on different waves -> QK-MFMA overlaps softmax-VALU cross-wave.
//  * lo waves barrier-idle for kt > qt_lo (no issue slots consumed).
//  * all 8 waves execute identical barrier counts (compute is gated,
//    barriers are not).

static __device__ __forceinline__ void stage_kv(
    unsigned short* bufp, const unsigned short* __restrict__ qkv,
    const unsigned short* __restrict__ vT, size_t tokb, int bh, int h,
    int k0, int w, int l)
{
  unsigned short* Kb = bufp;          // [128 key][64 d], XOR row&7
  unsigned short* Vb = bufp + 8192;   // [64 d][128 key], XOR row&15
  const int krow_l = l >> 3, kslot = l & 7;
  const int vrow_l = l >> 4, vslot = l & 15;
#pragma unroll
  for (int i = 0; i < 2; i++) {       // 8 waves x 2 instr x 8 rows = 128
    int rb = (w * 2 + i) * 8;
    int row = rb + krow_l;
    int ck = kslot ^ (row & 7);
    const unsigned short* g = qkv + (tokb + k0 + row) * C3 + C1 + h * 64 + ck * 8;
    __builtin_amdgcn_global_load_lds((gv_t*)g, (lv_t*)&Kb[rb * 64], 16, 0, 0);
  }
#pragma unroll
  for (int i = 0; i < 2; i++) {       // 8 waves x 2 instr x 4 rows = 64
    int rb = (w * 2 + i) * 4;
    int row = rb + vrow_l;
    int ck = vslot ^ (row & 15);
    const unsigned short* g = vT + ((size_t)bh * 64 + row) * SEQ + k0 + ck * 8;
    __builtin_amdgcn_global_load_lds((gv_t*)g, (lv_t*)&Vb[rb * 128], 16, 0, 0);
  }
}

// one 128-key tile for one q-tile: S^T=K@Q^T -> exp2 -> O^T += V^T@P^T
// w4 = wave's q-subblock (0..3) within the 128-row q-tile.
static __device__ __forceinline__ void attn_tile(
    f32x16* O, float& lrun, const bf16x8* qf,
    const unsigned short* Kb, const unsigned short* Vb,
    bool diag, int k0, int qmy, int w4, int l31, int hl)
{
#pragma unroll
  for (int ht = 0; ht < 2; ht++) {
    if (diag && (ht * 2 > w4)) continue;    // whole half beyond diagonal
    const bool two = !diag || (ht * 2 + 1 <= w4);

#pragma unroll
    for (int lm = 0; lm < 2; lm++) {        // one 32-key sub-tile end-to-end
      if (lm == 1 && !two) continue;
      const int mt = ht * 2 + lm;

      // S^T = K @ Q^T : C[key][q]; acc init -16 = softmax shift
      f32x16 stL;
#pragma unroll
      for (int i = 0; i < 16; i++) stL[i] = -16.f;
      {
        int row = mt * 32 + l31;
        const unsigned short* kr = &Kb[row * 64];
        __builtin_amdgcn_s_setprio(1);
#pragma unroll
        for (int ks = 0; ks < 4; ks++) {
          bf16x8 a = *(const bf16x8*)&kr[((((ks << 1) | hl)) ^ (row & 7)) * 8];
          stL = __builtin_amdgcn_mfma_f32_32x32x16_bf16(a, qf[ks], stL, 0, 0, 0);
        }
        __builtin_amdgcn_s_setprio(0);
      }

      if (diag && mt == w4) {  // partial mask (compile-time index, runtime compare)
#pragma unroll
        for (int r = 0; r < 16; r++) {
          int key = k0 + w4 * 32 + (r & 3) + ((r >> 2) << 3) + (hl << 2);
          if (key > qmy) stL[r] = -1e30f;
        }
      }

      // fixed-max softmax: P = exp2(S - 16); psum via 4 parallel accumulators
      float ps0 = 0.f, ps1 = 0.f, ps2 = 0.f, ps3 = 0.f;
      unsigned pk[8];
#pragma unroll
      for (int r = 0; r < 16; r += 4) {
        float p0 = EXP2(stL[r]);
        float p1 = EXP2(stL[r + 1]);
        float p2 = EXP2(stL[r + 2]);
        float p3 = EXP2(stL[r + 3]);
        ps0 += p0; ps1 += p1; ps2 += p2; ps3 += p3;
        pk[(r >> 1)]     = pk2(p0, p1);
        pk[(r >> 1) + 1] = pk2(p2, p3);
      }
      lrun += (ps0 + ps1) + (ps2 + ps3);

      // V fragments batched upfront (one LDS latency hop, not four)
      bf16x8 vf[2][2];
#pragma unroll
      for (int e = 0; e < 2; e++) {
        int kk = ht * 4 + lm * 2 + e;
#pragma unroll
        for (int dt = 0; dt < 2; dt++) {
          int row = dt * 32 + l31;
          vf[e][dt] = *(const bf16x8*)&Vb[row * 128 + (((2 * kk + hl)) ^ (row & 15)) * 8];
        }
      }

      // O^T += V^T @ P^T (2 ksteps of 16 keys); permlane32_swap builds B-frag
#pragma unroll
      for (int e = 0; e < 2; e++) {
        union { unsigned u[4]; bf16x8 v; } Bf;
        plswap(pk[4 * e],     pk[4 * e + 2], Bf.u[0], Bf.u[2]);
        plswap(pk[4 * e + 1], pk[4 * e + 3], Bf.u[1], Bf.u[3]);
        __builtin_amdgcn_s_setprio(1);
        O[0] = __builtin_amdgcn_mfma_f32_32x32x16_bf16(vf[e][0], Bf.v, O[0], 0, 0, 0);
        O[1] = __builtin_amdgcn_mfma_f32_32x32x16_bf16(vf[e][1], Bf.v, O[1], 0, 0, 0);
        __builtin_amdgcn_s_setprio(0);
      }
    }
  }
}

// epilogue: O^T (C-layout) -> LDS [q][d] -> coalesced bf16 store.
// qwbase = global row of this wave's first q; w = wave id (LDS region).
static __device__ __forceinline__ void attn_epi(
    const f32x16* O, float lrun, unsigned short* buf,
    unsigned short* __restrict__ att, size_t tokb, int qwbase, int h,
    int w, int l, int l31, int hl)
{
  lrun += __shfl_xor(lrun, 32, 64);  // combine q halves
  float linv = __builtin_amdgcn_rcpf(lrun);
  unsigned* epi32 = (unsigned*)buf;
  const int base = w * 2304 + l31 * 72;
#pragma unroll
  for (int dt = 0; dt < 2; dt++)
#pragma unroll
    for (int c = 0; c < 4; c++) {
      int d0 = dt * 32 + c * 8 + hl * 4;
      epi32[(base + d0) >> 1]     = rne2(O[dt][4 * c] * linv, O[dt][4 * c + 1] * linv);
      epi32[(base + d0 + 2) >> 1] = rne2(O[dt][4 * c + 2] * linv, O[dt][4 * c + 3] * linv);
    }
  __builtin_amdgcn_s_waitcnt(0);  // lgkm drain before cross-lane read (same wave)
  {
    int q = l >> 1, hf = l & 1;
    const unsigned short* ep = &buf[w * 2304 + q * 72 + hf * 32];
    unsigned short* og = att + (tokb + qwbase + q) * C1 + h * 64 + hf * 32;
#pragma unroll
    for (int c2 = 0; c2 < 4; c2++)
      *(bf16x8*)(og + c2 * 8) = *(const bf16x8*)&ep[c2 * 8];
  }
}

__global__ __launch_bounds__(512, 2) void k_attn(
    const unsigned short* __restrict__ qkv, const unsigned short* __restrict__ vT,
    unsigned short* __restrict__ att)
{
  __shared__ unsigned short buf[2][16384];  // per buf: Ks 128x64 | Vt 64x128
  const int tid = threadIdx.x;
  const int w = tid >> 6, l = tid & 63;
  const int w4 = w & 3;
  const bool hi = (w < 4);
  const int l31 = l & 31, hl = l >> 5;
  const int bh = blockIdx.x, b = bh >> 4, h = bh & 15;
  const int yq = blockIdx.y;                // 0..7
  const int qt_lo = yq, qt_hi = 15 - yq;    // paired q-tiles: uniform work 17
  const int myqt = hi ? qt_hi : qt_lo;
  const int q0 = myqt << 7;
  const int nkt = qt_hi + 1;
  const size_t tokb = (size_t)b * SEQ;
  const int qw = q0 + w4 * 32;
  const int qmy = qw + l31;

  // Q B-frags (global, once): B[k=d][n=q], k = hl*8+j within kstep
  bf16x8 qf[4];
  {
    const unsigned short* qp = qkv + (tokb + qw + l31) * C3 + h * 64 + hl * 8;
#pragma unroll
    for (int ks = 0; ks < 4; ks++) qf[ks] = *(const bf16x8*)(qp + ks * 16);
  }

  f32x16 O[2];
#pragma unroll
  for (int i = 0; i < 16; i++) { O[0][i] = 0.f; O[1][i] = 0.f; }
  float lrun = 0.f;

  // prologue: stage tile 0 (all 8 waves cooperate)
  stage_kv(&buf[0][0], qkv, vT, tokb, bh, h, 0, w, l);

  int cur = 0;
  for (int kt = 0; kt < nkt; kt++) {
    asm volatile("s_waitcnt vmcnt(0)" ::: "memory");  // own stage of buf[cur] landed
    __builtin_amdgcn_s_barrier();                      // everyone's landed; prev reads done
    if (kt + 1 < nkt)
      stage_kv(&buf[cur ^ 1][0], qkv, vT, tokb, bh, h, (kt + 1) << 7, w, l);

    if (kt <= myqt)   // hi waves: always true; lo waves idle past their tile
      attn_tile(O, lrun, qf, &buf[cur][0], &buf[cur][8192],
                kt == myqt, kt << 7, qmy, w4, l31, hl);

    cur ^= 1;
  }

  __syncthreads();  // all waves done reading buf before epilogue overlay
  attn_epi(O, lrun, &buf[0][0], att, tokb, qw, h, w, l, l31, hl);
}

extern "C" void kernel_launch(void* const* d_in, const int* in_sizes, int n_in,
                              void* d_out, int out_size, void* d_ws, size_t ws_size,
                              hipStream_t stream) {
  const float* x     = (const float*)d_in[0];
  const float* w_qkv = (const float*)d_in[1];
  const float* w_out = (const float*)d_in[2];
  const float* b_out = (const float*)d_in[3];
  float* out = (float*)d_out;

  unsigned short* xb  = (unsigned short*)d_ws;
  unsigned short* wqb = xb  + (size_t)8192 * 1024;
  unsigned short* wob = wqb + (size_t)3072 * 1024;
  unsigned short* qkv = wob + (size_t)1024 * 1024;
  unsigned short* att = qkv + (size_t)8192 * 3072;
  unsigned short* vT  = att + (size_t)8192 * 1024;

  k_cvt3<<<3072, 256, 0, stream>>>(x, w_qkv, w_out, xb, wqb, wob);
  k_gemm<0><<<dim3(24, 64), 256, 0, stream>>>(xb, wqb, (void*)qkv, nullptr, vT, 8192, 3072, 1024);
  k_attn<<<dim3(64, 8), 512, 0, stream>>>(qkv, vT, att);
  k_gemm<1><<<dim3(8, 64), 256, 0, stream>>>(att, wob, (void*)out, b_out, nullptr, 8192, 1024, 1024);
}